// Round 1
// baseline (547.112 us; speedup 1.0000x reference)
//
#include <hip/hip_runtime.h>

#define F_IN  128
#define H_MID 16
#define C_OUT 8

// ---- degree: deg[i] = 1 (self loop) + sum of incoming edge weights ----
__global__ void k_init_deg(float* __restrict__ deg, int N) {
    int i = blockIdx.x * blockDim.x + threadIdx.x;
    if (i < N) deg[i] = 1.0f;
}

__global__ void k_scatter_deg(const int* __restrict__ dst, const float* __restrict__ ew,
                              float* __restrict__ deg, int E) {
    int e = blockIdx.x * blockDim.x + threadIdx.x;
    if (e < E) atomicAdd(&deg[dst[e]], ew[e]);
}

__global__ void k_rsqrt(float* __restrict__ deg, int N) {
    int i = blockIdx.x * blockDim.x + threadIdx.x;
    if (i < N) {
        float v = deg[i];
        deg[i] = (v > 0.0f) ? rsqrtf(v) : 0.0f;
    }
}

// ---- layer-1 GEMM: h1 = x @ W1 ; a1 = h1*dis^2 + b1 (self-loop + bias init) ----
__global__ void k_gemm1(const float* __restrict__ x, const float* __restrict__ W1,
                        const float* __restrict__ b1, const float* __restrict__ dis,
                        float* __restrict__ h1, float* __restrict__ a1, int N) {
    __shared__ float W1s[F_IN * H_MID];
    for (int i = threadIdx.x; i < F_IN * H_MID; i += blockDim.x) W1s[i] = W1[i];
    __syncthreads();
    const int c   = threadIdx.x & 15;
    const int lr  = threadIdx.x >> 4;
    const int rpb = blockDim.x >> 4;   // rows per block iteration (16 for 256 threads)
    for (long long row = (long long)blockIdx.x * rpb + lr; row < N;
         row += (long long)gridDim.x * rpb) {
        const float4* xr = reinterpret_cast<const float4*>(x + row * F_IN);
        float acc = 0.0f;
#pragma unroll
        for (int k4 = 0; k4 < F_IN / 4; ++k4) {
            float4 v = xr[k4];
            acc = fmaf(v.x, W1s[(k4 * 4 + 0) * H_MID + c], acc);
            acc = fmaf(v.y, W1s[(k4 * 4 + 1) * H_MID + c], acc);
            acc = fmaf(v.z, W1s[(k4 * 4 + 2) * H_MID + c], acc);
            acc = fmaf(v.w, W1s[(k4 * 4 + 3) * H_MID + c], acc);
        }
        h1[row * H_MID + c] = acc;
        float di = dis[row];
        a1[row * H_MID + c] = fmaf(acc, di * di, b1[c]);
    }
}

// ---- edge aggregation: out[dst] += h[src] * dis[src]*ew*dis[dst] ----
template <int CH>
__global__ void k_agg(const int* __restrict__ src, const int* __restrict__ dst,
                      const float* __restrict__ ew, const float* __restrict__ dis,
                      const float* __restrict__ h, float* __restrict__ out, long long E) {
    const int LOG = (CH == 16) ? 4 : 3;
    const long long total  = E << LOG;
    const long long stride = (long long)gridDim.x * blockDim.x;
    for (long long idx = (long long)blockIdx.x * blockDim.x + threadIdx.x; idx < total;
         idx += stride) {
        const long long e = idx >> LOG;
        const int c = (int)(idx & (CH - 1));
        const int s = src[e];
        const int d = dst[e];
        const float norm = dis[s] * ew[e] * dis[d];
        atomicAdd(out + (long long)d * CH + c, h[(long long)s * CH + c] * norm);
    }
}

// ---- layer-2 GEMM: h2 = relu(a1) @ W2 ; out = h2*dis^2 + b2 ----
__global__ void k_gemm2(const float* __restrict__ a1, const float* __restrict__ W2,
                        const float* __restrict__ b2, const float* __restrict__ dis,
                        float* __restrict__ h2, float* __restrict__ out, int N) {
    __shared__ float W2s[H_MID * C_OUT];
    if (threadIdx.x < H_MID * C_OUT) W2s[threadIdx.x] = W2[threadIdx.x];
    __syncthreads();
    const int c   = threadIdx.x & 7;
    const int lr  = threadIdx.x >> 3;
    const int rpb = blockDim.x >> 3;   // 32 rows per 256-thread block
    for (long long row = (long long)blockIdx.x * rpb + lr; row < N;
         row += (long long)gridDim.x * rpb) {
        const float4* ar = reinterpret_cast<const float4*>(a1 + row * H_MID);
        float acc = 0.0f;
#pragma unroll
        for (int k4 = 0; k4 < H_MID / 4; ++k4) {
            float4 v = ar[k4];
            acc = fmaf(fmaxf(v.x, 0.0f), W2s[(k4 * 4 + 0) * C_OUT + c], acc);
            acc = fmaf(fmaxf(v.y, 0.0f), W2s[(k4 * 4 + 1) * C_OUT + c], acc);
            acc = fmaf(fmaxf(v.z, 0.0f), W2s[(k4 * 4 + 2) * C_OUT + c], acc);
            acc = fmaf(fmaxf(v.w, 0.0f), W2s[(k4 * 4 + 3) * C_OUT + c], acc);
        }
        h2[row * C_OUT + c] = acc;
        float di = dis[row];
        out[row * C_OUT + c] = fmaf(acc, di * di, b2[c]);
    }
}

extern "C" void kernel_launch(void* const* d_in, const int* in_sizes, int n_in,
                              void* d_out, int out_size, void* d_ws, size_t ws_size,
                              hipStream_t stream) {
    const float* x  = (const float*)d_in[0];
    const int*   ei = (const int*)d_in[1];
    const float* ew = (const float*)d_in[2];
    const float* W1 = (const float*)d_in[3];
    const float* b1 = (const float*)d_in[4];
    const float* W2 = (const float*)d_in[5];
    const float* b2 = (const float*)d_in[6];
    float* out = (float*)d_out;

    const int H   = in_sizes[4];            // 16
    const int Fin = in_sizes[3] / H;        // 128
    const int N   = in_sizes[0] / Fin;      // 100000
    const long long E = in_sizes[2];        // 1600000
    const int* src = ei;
    const int* dst = ei + E;

    // workspace layout
    char* ws = (char*)d_ws;
    size_t off = 0;
    auto alloc = [&](size_t bytes) {
        void* p = ws + off;
        off = (off + bytes + 255) & ~(size_t)255;
        return p;
    };
    float* dis = (float*)alloc((size_t)N * sizeof(float));
    float* h1  = (float*)alloc((size_t)N * H_MID * sizeof(float));
    float* a1  = (float*)alloc((size_t)N * H_MID * sizeof(float));
    float* h2  = (float*)alloc((size_t)N * C_OUT * sizeof(float));
    (void)ws_size; (void)n_in; (void)out_size;

    const int B = 256;
    // 1. degrees -> dis (in place)
    k_init_deg<<<(N + B - 1) / B, B, 0, stream>>>(dis, N);
    k_scatter_deg<<<(int)((E + B - 1) / B), B, 0, stream>>>(dst, ew, dis, (int)E);
    k_rsqrt<<<(N + B - 1) / B, B, 0, stream>>>(dis, N);
    // 2. layer-1 GEMM + a1 init (self loop + bias)
    k_gemm1<<<(N + 15) / 16, B, 0, stream>>>(x, W1, b1, dis, h1, a1, N);
    // 3. layer-1 edge aggregation (16 channels)
    k_agg<H_MID><<<8192, B, 0, stream>>>(src, dst, ew, dis, h1, a1, E);
    // 4. relu + layer-2 GEMM + out init (self loop + bias)
    k_gemm2<<<(N + 31) / 32, B, 0, stream>>>(a1, W2, b2, dis, h2, out, N);
    // 5. layer-2 edge aggregation (8 channels) straight into d_out
    k_agg<C_OUT><<<8192, B, 0, stream>>>(src, dst, ew, dis, h2, out, E);
}

// Round 2
// 325.532 us; speedup vs baseline: 1.6807x; 1.6807x over previous
//
#include <hip/hip_runtime.h>

#define F_IN  128
#define H_MID 16
#define C_OUT 8
#define XS_PAD (F_IN + 4)   // pad to 132 floats: b128 reads from 4 row-groups hit distinct bank quads

// ---- degree: deg[i] = 1 (self loop) + sum of incoming edge weights ----
__global__ void k_init_deg(float* __restrict__ deg, int N) {
    int i = blockIdx.x * blockDim.x + threadIdx.x;
    if (i < N) deg[i] = 1.0f;
}

__global__ void k_scatter_deg(const int* __restrict__ dst, const float* __restrict__ ew,
                              float* __restrict__ deg, int E) {
    int e = blockIdx.x * blockDim.x + threadIdx.x;
    if (e < E) atomicAdd(&deg[dst[e]], ew[e]);
}

__global__ void k_rsqrt(float* __restrict__ deg, int N) {
    int i = blockIdx.x * blockDim.x + threadIdx.x;
    if (i < N) {
        float v = deg[i];
        deg[i] = (v > 0.0f) ? rsqrtf(v) : 0.0f;
    }
}

// ---- layer-1 GEMM: h1 = x @ W1 ; a1 = h1*dis^2 + b1 (self-loop + bias init) ----
// LDS-staged: coalesced float4 global loads of a 64-row x tile, compute from LDS.
__global__ void __launch_bounds__(256) k_gemm1(
        const float* __restrict__ x, const float* __restrict__ W1,
        const float* __restrict__ b1, const float* __restrict__ dis,
        float* __restrict__ h1, float* __restrict__ a1, int N) {
    __shared__ float xs[64 * XS_PAD];
    __shared__ float W1s[F_IN * H_MID];
    const int t = threadIdx.x;
    for (int i = t; i < F_IN * H_MID; i += 256) W1s[i] = W1[i];

    const int c  = t & 15;
    const int r0 = t >> 4;

    for (long long tile = (long long)blockIdx.x * 64; tile < N;
         tile += (long long)gridDim.x * 64) {
        const int rows = (int)((N - tile < 64) ? (N - tile) : 64);
        __syncthreads();
        // coalesced stage: thread t loads float4 #i at linear index, 2048 float4 per full tile
        const int nf4 = rows * (F_IN / 4);
        const float4* xg = reinterpret_cast<const float4*>(x + tile * F_IN);
        for (int i = t; i < nf4; i += 256) {
            const int r  = i >> 5;          // /32 float4 per row
            const int k4 = i & 31;
            *reinterpret_cast<float4*>(&xs[r * XS_PAD + k4 * 4]) = xg[i];
        }
        __syncthreads();
        for (int rr = r0; rr < rows; rr += 16) {
            const float* xr = &xs[rr * XS_PAD];
            float acc = 0.0f;
#pragma unroll
            for (int k4 = 0; k4 < F_IN / 4; ++k4) {
                float4 v = *reinterpret_cast<const float4*>(&xr[k4 * 4]);
                acc = fmaf(v.x, W1s[(k4 * 4 + 0) * H_MID + c], acc);
                acc = fmaf(v.y, W1s[(k4 * 4 + 1) * H_MID + c], acc);
                acc = fmaf(v.z, W1s[(k4 * 4 + 2) * H_MID + c], acc);
                acc = fmaf(v.w, W1s[(k4 * 4 + 3) * H_MID + c], acc);
            }
            const long long row = tile + rr;
            h1[row * H_MID + c] = acc;
            float di = dis[row];
            a1[row * H_MID + c] = fmaf(acc, di * di, b1[c]);
        }
    }
}

// ---- edge aggregation: out[dst] += h[src] * dis[src]*ew*dis[dst] ----
template <int CH>
__global__ void k_agg(const int* __restrict__ src, const int* __restrict__ dst,
                      const float* __restrict__ ew, const float* __restrict__ dis,
                      const float* __restrict__ h, float* __restrict__ out, long long E) {
    const int LOG = (CH == 16) ? 4 : 3;
    const long long total  = E << LOG;
    const long long stride = (long long)gridDim.x * blockDim.x;
    for (long long idx = (long long)blockIdx.x * blockDim.x + threadIdx.x; idx < total;
         idx += stride) {
        const long long e = idx >> LOG;
        const int c = (int)(idx & (CH - 1));
        const int s = src[e];
        const int d = dst[e];
        const float norm = dis[s] * ew[e] * dis[d];
        atomicAdd(out + (long long)d * CH + c, h[(long long)s * CH + c] * norm);
    }
}

// ---- layer-2 GEMM: h2 = relu(a1) @ W2 ; out = h2*dis^2 + b2 ----
__global__ void k_gemm2(const float* __restrict__ a1, const float* __restrict__ W2,
                        const float* __restrict__ b2, const float* __restrict__ dis,
                        float* __restrict__ h2, float* __restrict__ out, int N) {
    __shared__ float W2s[H_MID * C_OUT];
    if (threadIdx.x < H_MID * C_OUT) W2s[threadIdx.x] = W2[threadIdx.x];
    __syncthreads();
    const int c   = threadIdx.x & 7;
    const int lr  = threadIdx.x >> 3;
    const int rpb = blockDim.x >> 3;   // 32 rows per 256-thread block
    for (long long row = (long long)blockIdx.x * rpb + lr; row < N;
         row += (long long)gridDim.x * rpb) {
        const float4* ar = reinterpret_cast<const float4*>(a1 + row * H_MID);
        float acc = 0.0f;
#pragma unroll
        for (int k4 = 0; k4 < H_MID / 4; ++k4) {
            float4 v = ar[k4];
            acc = fmaf(fmaxf(v.x, 0.0f), W2s[(k4 * 4 + 0) * C_OUT + c], acc);
            acc = fmaf(fmaxf(v.y, 0.0f), W2s[(k4 * 4 + 1) * C_OUT + c], acc);
            acc = fmaf(fmaxf(v.z, 0.0f), W2s[(k4 * 4 + 2) * C_OUT + c], acc);
            acc = fmaf(fmaxf(v.w, 0.0f), W2s[(k4 * 4 + 3) * C_OUT + c], acc);
        }
        h2[row * C_OUT + c] = acc;
        float di = dis[row];
        out[row * C_OUT + c] = fmaf(acc, di * di, b2[c]);
    }
}

extern "C" void kernel_launch(void* const* d_in, const int* in_sizes, int n_in,
                              void* d_out, int out_size, void* d_ws, size_t ws_size,
                              hipStream_t stream) {
    const float* x  = (const float*)d_in[0];
    const int*   ei = (const int*)d_in[1];
    const float* ew = (const float*)d_in[2];
    const float* W1 = (const float*)d_in[3];
    const float* b1 = (const float*)d_in[4];
    const float* W2 = (const float*)d_in[5];
    const float* b2 = (const float*)d_in[6];
    float* out = (float*)d_out;

    const int H   = in_sizes[4];            // 16
    const int Fin = in_sizes[3] / H;        // 128
    const int N   = in_sizes[0] / Fin;      // 100000
    const long long E = in_sizes[2];        // 1600000
    const int* src = ei;
    const int* dst = ei + E;

    // workspace layout
    char* ws = (char*)d_ws;
    size_t off = 0;
    auto alloc = [&](size_t bytes) {
        void* p = ws + off;
        off = (off + bytes + 255) & ~(size_t)255;
        return p;
    };
    float* dis = (float*)alloc((size_t)N * sizeof(float));
    float* h1  = (float*)alloc((size_t)N * H_MID * sizeof(float));
    float* a1  = (float*)alloc((size_t)N * H_MID * sizeof(float));
    float* h2  = (float*)alloc((size_t)N * C_OUT * sizeof(float));
    (void)ws_size; (void)n_in; (void)out_size;

    const int B = 256;
    // 1. degrees -> dis (in place)
    k_init_deg<<<(N + B - 1) / B, B, 0, stream>>>(dis, N);
    k_scatter_deg<<<(int)((E + B - 1) / B), B, 0, stream>>>(dst, ew, dis, (int)E);
    k_rsqrt<<<(N + B - 1) / B, B, 0, stream>>>(dis, N);
    // 2. layer-1 GEMM + a1 init (self loop + bias), LDS-staged coalesced
    k_gemm1<<<(N + 63) / 64, B, 0, stream>>>(x, W1, b1, dis, h1, a1, N);
    // 3. layer-1 edge aggregation (16 channels)
    k_agg<H_MID><<<8192, B, 0, stream>>>(src, dst, ew, dis, h1, a1, E);
    // 4. relu + layer-2 GEMM + out init (self loop + bias)
    k_gemm2<<<(N + 31) / 32, B, 0, stream>>>(a1, W2, b2, dis, h2, out, N);
    // 5. layer-2 edge aggregation (8 channels) straight into d_out
    k_agg<C_OUT><<<8192, B, 0, stream>>>(src, dst, ew, dis, h2, out, E);
}